// Round 14
// baseline (195.324 us; speedup 1.0000x reference)
//
#include <hip/hip_runtime.h>
#include <stdint.h>
#include <stddef.h>

typedef __attribute__((ext_vector_type(8))) short bf16x8;
typedef __attribute__((ext_vector_type(4))) float f32x4;
typedef __attribute__((ext_vector_type(16))) float f32x16;

#define DMODEL 1536
#define TSEQ   2048
#define HDIM   128
#define NBR    3
#define NHB    4      // heads per branch
#define MROWS  4096   // B*T

__device__ __forceinline__ float bf2f(unsigned short u) {
  union { unsigned int i; float f; } v; v.i = ((unsigned int)u) << 16; return v.f;
}
__device__ __forceinline__ unsigned short f2bf(float f) {
  union { float f; unsigned int i; } v; v.f = f;
  unsigned int r = v.i + 0x7fffu + ((v.i >> 16) & 1u);
  return (unsigned short)(r >> 16);
}
__device__ __forceinline__ unsigned int cvtpk(float lo, float hi) {
  unsigned int r;
  asm("v_cvt_pk_bf16_f32 %0, %1, %2" : "=v"(r) : "v"(lo), "v"(hi));
  return r;
}
__device__ __forceinline__ void plswap(unsigned int& a, unsigned int& b) {
  asm("v_permlane32_swap_b32 %0, %1" : "+v"(a), "+v"(b));
}
__device__ __forceinline__ void gload_lds16(const void* g, void* l) {
  __builtin_amdgcn_global_load_lds((__attribute__((address_space(1))) void*)g,
                                   (__attribute__((address_space(3))) void*)l,
                                   16, 0, 0);
}

// ---------------------------------------------------------------------------
// f32 -> bf16 conversion kernels (pre-pass)
// ---------------------------------------------------------------------------
__global__ __launch_bounds__(256) void k_cvt(const float* __restrict__ src,
                                             unsigned short* __restrict__ dst,
                                             int n4) {
  int i = blockIdx.x * 256 + threadIdx.x;
  if (i >= n4) return;
  float4 v = ((const float4*)src)[i];
  ushort4 o;
  o.x = f2bf(v.x); o.y = f2bf(v.y); o.z = f2bf(v.z); o.w = f2bf(v.w);
  ((ushort4*)dst)[i] = o;
}

struct W9 { const float* w[9]; };

__global__ __launch_bounds__(256) void k_cvt9(W9 ws, unsigned short* __restrict__ dst,
                                              int n4) {
  int seg = blockIdx.y;
  const float* __restrict__ src = ws.w[seg];
  unsigned short* __restrict__ d = dst + (size_t)seg * (size_t)n4 * 4;
  int i = blockIdx.x * 256 + threadIdx.x;
  if (i >= n4) return;
  float4 v = ((const float4*)src)[i];
  ushort4 o;
  o.x = f2bf(v.x); o.y = f2bf(v.y); o.z = f2bf(v.z); o.w = f2bf(v.w);
  ((ushort4*)d)[i] = o;
}

// ---------------------------------------------------------------------------
// Pipelined GEMM (R8 configuration — measured 69.6 us / 833 TF / 0 conflicts):
// C = A[4096,1536] * B[N,1536]^T, bf16, tile 128x192x64, 8 waves (2Mx4N).
// A and B both via global_load_lds + XOR swizzle; counted s_waitcnt vmcnt(5).
// NOTE: B-direct-to-register (R10-R12) spills under the 64-VGPR occupancy cap.
// ---------------------------------------------------------------------------
#define GBM 128
#define GBN 192
#define GBK 64
#define GK  1536
#define GNT (GK / GBK)   // 24 K-tiles

template<int EPI>
__global__ __launch_bounds__(512, 4) void k_gemm8(
    const unsigned short* __restrict__ A, const unsigned short* __restrict__ Bw,
    unsigned short* __restrict__ Qs, unsigned short* __restrict__ Ksl,
    unsigned short* __restrict__ Vs, float* __restrict__ Cout)
{
  __shared__ __align__(16) unsigned short As[2 * GBM * GBK];   // 32 KiB
  __shared__ __align__(16) unsigned short Bs[2 * GBN * GBK];   // 48 KiB

  const int t = threadIdx.x, ln = t & 63, w = t >> 6;
  const int wm = w >> 2, wn = w & 3, g = ln >> 4, li = ln & 15;

  const int nwg = gridDim.x * gridDim.y;
  const int lid = blockIdx.y * gridDim.x + blockIdx.x;
  const int s = (lid & 7) * (nwg >> 3) + (lid >> 3);
  const int m0 = (s & 31) * GBM;
  const int n0 = (s >> 5) * GBN;

  f32x4 zero4 = {0.f, 0.f, 0.f, 0.f};
  f32x4 acc[4][3];
#pragma unroll
  for (int i = 0; i < 4; ++i)
#pragma unroll
    for (int j = 0; j < 3; ++j) acc[i][j] = zero4;

  auto STAGE = [&](int p, int kt) {
    const unsigned short* Ag = A + (size_t)m0 * GK + kt * GBK;
    unsigned short* Al = As + p * (GBM * GBK);
#pragma unroll
    for (int i = 0; i < 2; ++i) {
      int ch = i * 512 + t; int r = ch >> 3, c = ch & 7;
      gload_lds16(Ag + (size_t)r * GK + ((c ^ (r & 7)) * 8), Al + ch * 8);
    }
    const unsigned short* Bg = Bw + (size_t)n0 * GK + kt * GBK;
    unsigned short* Bl = Bs + p * (GBN * GBK);
#pragma unroll
    for (int i = 0; i < 3; ++i) {
      int ch = i * 512 + t; int r = ch >> 3, c = ch & 7;
      gload_lds16(Bg + (size_t)r * GK + ((c ^ (r & 7)) * 8), Bl + ch * 8);
    }
  };

  STAGE(0, 0);
  STAGE(1, 1);

  for (int kt = 0; kt < GNT; ++kt) {
    const int cur = kt & 1;
    if (kt < GNT - 1) { asm volatile("s_waitcnt vmcnt(5)" ::: "memory"); }
    else              { asm volatile("s_waitcnt vmcnt(0)" ::: "memory"); }
    __builtin_amdgcn_sched_barrier(0);
    __builtin_amdgcn_s_barrier();
    __builtin_amdgcn_sched_barrier(0);
    asm volatile("" ::: "memory");

    const unsigned short* Al = As + cur * (GBM * GBK);
    const unsigned short* Bl = Bs + cur * (GBN * GBK);
#pragma unroll
    for (int kh = 0; kh < 2; ++kh) {
      bf16x8 af[4], bfn[3];
#pragma unroll
      for (int mf = 0; mf < 4; ++mf) {
        int r = wm * 64 + mf * 16 + li;
        af[mf] = *(const bf16x8*)(Al + r * 64 + (((kh * 4 + g) ^ (li & 7)) * 8));
      }
#pragma unroll
      for (int nf = 0; nf < 3; ++nf) {
        int r = wn * 48 + nf * 16 + li;
        bfn[nf] = *(const bf16x8*)(Bl + r * 64 + (((kh * 4 + g) ^ (li & 7)) * 8));
      }
      __builtin_amdgcn_s_setprio(1);
#pragma unroll
      for (int mf = 0; mf < 4; ++mf)
#pragma unroll
        for (int nf = 0; nf < 3; ++nf)
          acc[mf][nf] = __builtin_amdgcn_mfma_f32_16x16x32_bf16(
              af[mf], bfn[nf], acc[mf][nf], 0, 0, 0);
      __builtin_amdgcn_s_setprio(0);
    }
    asm volatile("" ::: "memory");
    __builtin_amdgcn_sched_barrier(0);
    __builtin_amdgcn_s_barrier();
    __builtin_amdgcn_sched_barrier(0);
    if (kt + 2 < GNT) STAGE(cur, kt + 2);
  }

  // epilogue (coalesced: lane li covers consecutive cols)
#pragma unroll
  for (int mf = 0; mf < 4; ++mf)
#pragma unroll
    for (int nf = 0; nf < 3; ++nf)
#pragma unroll
      for (int rr = 0; rr < 4; ++rr) {
        int row = m0 + wm * 64 + mf * 16 + g * 4 + rr;
        int col = n0 + wn * 48 + nf * 16 + li;
        if (EPI == 0) {
          int mat = col >> 9, within = col & 511;
          int br = mat / 3, qkv = mat % 3;
          int b = row >> 11, tt = row & 2047;
          int h = within >> 7, d = within & 127;
          unsigned short* dst = (qkv == 0) ? Qs : (qkv == 1) ? Ksl : Vs;
          size_t off = ((size_t)((br * 2 + b) * 4 + h) * TSEQ + tt) * HDIM + d;
          dst[off] = f2bf(acc[mf][nf][rr]);
        } else {
          Cout[(size_t)row * DMODEL + col] = acc[mf][nf][rr];
        }
      }
}

// ---------------------------------------------------------------------------
// RMSNorm + RoPE in place on Q,K slabs (bf16). One wave per row.
// ---------------------------------------------------------------------------
__global__ __launch_bounds__(256) void k_rope(
    unsigned short* __restrict__ Q, unsigned short* __restrict__ K,
    const float* __restrict__ qw, const float* __restrict__ kw)
{
  const int t = threadIdx.x, ln = t & 63, w = t >> 6;
  const int rid = blockIdx.x * 4 + w;          // 0..49151
  const int tt  = rid & (TSEQ - 1);
  const size_t base = (size_t)rid * HDIM;

  const float ang = (float)tt * exp2f(-0.31143075464f * (float)ln);
  float s, c;
  sincosf(ang, &s, &c);

#pragma unroll
  for (int which = 0; which < 2; ++which) {
    unsigned short* P = which ? K : Q;
    const float* Wn = which ? kw : qw;
    float x1 = bf2f(P[base + ln]);
    float x2 = bf2f(P[base + 64 + ln]);
    float ss = x1 * x1 + x2 * x2;
#pragma unroll
    for (int off = 1; off < 64; off <<= 1) ss += __shfl_xor(ss, off, 64);
    float rr = rsqrtf(ss * (1.0f / 128.0f) + 1.1920928955078125e-07f);
    float y1 = x1 * rr * Wn[ln];
    float y2 = x2 * rr * Wn[64 + ln];
    P[base + ln]      = f2bf(y1 * c - y2 * s);
    P[base + 64 + ln] = f2bf(y2 * c + y1 * s);
  }
}

// ---------------------------------------------------------------------------
// V transpose: V[slab][t][d] -> VT[slab][d][t]. Tile 64t x 64d, LDS stride 65
// ---------------------------------------------------------------------------
__global__ __launch_bounds__(256) void k_vtrans(
    const unsigned short* __restrict__ V, unsigned short* __restrict__ VT)
{
  __shared__ unsigned short L[64 * 65];
  const int tb = blockIdx.x;          // t-tile 0..31
  const int db = blockIdx.y;          // d-tile 0..1
  const int sl = blockIdx.z;          // slab 0..23
  const size_t slab = (size_t)sl * (TSEQ * HDIM);
  const int t = threadIdx.x;

#pragma unroll
  for (int i = 0; i < 2; ++i) {
    int c = i * 256 + t;              // 512 chunks of 8 elems
    int trow = c >> 3, d0 = (c & 7) * 8;
    bf16x8 vv = *(const bf16x8*)(V + slab + (size_t)(tb*64 + trow) * HDIM + db*64 + d0);
#pragma unroll
    for (int j = 0; j < 8; ++j) L[trow * 65 + d0 + j] = (unsigned short)vv[j];
  }
  __syncthreads();
#pragma unroll
  for (int i = 0; i < 2; ++i) {
    int c = i * 256 + t;
    int drow = c >> 3, t0 = (c & 7) * 8;
    bf16x8 ov;
#pragma unroll
    for (int j = 0; j < 8; ++j) ov[j] = (short)L[(t0 + j) * 65 + drow];
    *(bf16x8*)(VT + slab + (size_t)(db*64 + drow) * TSEQ + tb*64 + t0) = ov;
  }
}

// ---------------------------------------------------------------------------
// Flash attention, 32x32x16 MFMA + split-K groups + in-register P.
// 8 waves: gid = w>>2 (k-group), wq = w&3 (q-chunk of 32). QBLK=128, KVBLK=64.
// R14: double-buffered per-group K/V LDS -> ONE barrier per visit (was 2).
// Per visit: write tile i+1 (regs) to parity p^1, prefetch tile i+2, compute
// from parity p, barrier. End-of-visit barrier proves both read-drain and
// write-visibility for the next visit.
// ---------------------------------------------------------------------------
#define ATT_SCALE 0.08838834764831845f

template<int MODE>
__device__ __forceinline__ void flash_phase(
    int qt, int bh,
    const unsigned short* __restrict__ Q, const unsigned short* __restrict__ K,
    const unsigned short* __restrict__ VT, unsigned short* __restrict__ AO,
    unsigned short* SH)
{
  const int b = bh >> 2, h = bh & 3;
  const int t = threadIdx.x, l = t & 63, w = t >> 6;
  const int hi = l >> 5, l31 = l & 31;
  const int wq = w & 3, gid = w >> 2;
  const size_t slab = (size_t)(MODE * 8 + bh) * (TSEQ * HDIM);
  const int q0 = qt * 128;

  // LDS layout (u16 units): group gid, parity p at gid*35840 + p*17920;
  // Ks = base (64x136), Vt = base + 8704 (128x72). Total 71680 u16 = 143360 B.

  bf16x8 qf[8];
  {
    const unsigned short* qp = Q + slab + (size_t)(q0 + wq*32 + l31) * HDIM + hi*8;
#pragma unroll
    for (int st = 0; st < 8; ++st) qf[st] = *(const bf16x8*)(qp + st*16);
  }

  f32x16 zero16;
#pragma unroll
  for (int e = 0; e < 16; ++e) zero16[e] = 0.f;
  f32x16 acc[4];
#pragma unroll
  for (int df = 0; df < 4; ++df) acc[df] = zero16;
  float m_run = -1e30f, l_run = 0.f;

  int n, ktbase, diagAt;
  if (MODE == 0)      { n = qt + 1;  ktbase = gid;          diagAt = n - 1; }
  else if (MODE == 1) { n = 16 - qt; ktbase = 2*qt + gid;   diagAt = 0; }
  else                { n = 16;      ktbase = gid;          diagAt = -1; }

  const int tl = t & 255;
  bf16x8 rk[4], rv[4];
  auto LOADT = [&](int kt) {
    const int k0 = kt * 64;
#pragma unroll
    for (int j = 0; j < 4; ++j) {
      int c = j * 256 + tl;
      rk[j] = *(const bf16x8*)(K  + slab + (size_t)(k0 + (c >> 4)) * HDIM + (c & 15) * 8);
      rv[j] = *(const bf16x8*)(VT + slab + (size_t)(c >> 3) * TSEQ + k0 + (c & 7) * 8);
    }
  };
  auto WRITE = [&](int p) {
    unsigned short* Kb = SH + gid * 35840 + p * 17920;
    unsigned short* Vb = Kb + 8704;
#pragma unroll
    for (int j = 0; j < 4; ++j) {
      int c = j * 256 + tl;
      *(bf16x8*)(Kb + (c >> 4) * 136 + (c & 15) * 8) = rk[j];
      *(bf16x8*)(Vb + (c >> 3) * 72  + (c & 7) * 8)  = rv[j];
    }
  };

  // prologue: tile0 -> buf0, tile1 -> regs
  LOADT(ktbase);
  __syncthreads();                 // prior phase's LDS use done
  WRITE(0);
  if (n > 1) LOADT(ktbase + 2);
  __syncthreads();                 // buf0 visible to all waves

  for (int i = 0; i < n; ++i) {
    const int p = i & 1;
    // stage tile i+1 into the other parity; prefetch tile i+2 into regs
    if (i + 1 < n) {
      WRITE(p ^ 1);
      if (i + 2 < n) LOADT(ktbase + 2 * (i + 2));
    }

    const int kt = ktbase + 2 * i;
    const int k0 = kt * 64;
    const unsigned short* KsG = SH + gid * 35840 + p * 17920;
    const unsigned short* VtG = KsG + 8704;

    f32x16 sf0 = zero16, sf1 = zero16;
#pragma unroll
    for (int st = 0; st < 8; ++st) {
      bf16x8 kf0 = *(const bf16x8*)(KsG + l31 * 136 + st*16 + hi*8);
      bf16x8 kf1 = *(const bf16x8*)(KsG + (32 + l31) * 136 + st*16 + hi*8);
      __builtin_amdgcn_s_setprio(1);
      sf0 = __builtin_amdgcn_mfma_f32_32x32x16_bf16(kf0, qf[st], sf0, 0, 0, 0);
      sf1 = __builtin_amdgcn_mfma_f32_32x32x16_bf16(kf1, qf[st], sf1, 0, 0, 0);
      __builtin_amdgcn_s_setprio(0);
    }

    float pf[32];
#pragma unroll
    for (int r = 0; r < 16; ++r) { pf[r] = sf0[r] * ATT_SCALE; pf[16+r] = sf1[r] * ATT_SCALE; }

    if (MODE != 2 && i == diagAt) {
      const int qg = q0 + wq*32 + l31;
#pragma unroll
      for (int f = 0; f < 2; ++f)
#pragma unroll
        for (int r = 0; r < 16; ++r) {
          int kg = k0 + f*32 + 4*hi + (r & 3) + 8*(r >> 2);
          bool ok = (MODE == 0) ? (kg <= qg) : (kg >= qg);
          if (!ok) pf[f*16 + r] = -1e30f;
        }
    }

    float m = pf[0];
#pragma unroll
    for (int j = 1; j < 32; ++j) m = fmaxf(m, pf[j]);
    m = fmaxf(m, __shfl_xor(m, 32, 64));

    if (__any(m > m_run)) {
      float mn = fmaxf(m_run, m);
      float alpha = __expf(m_run - mn);
      m_run = mn;
      l_run *= alpha;
#pragma unroll
      for (int df = 0; df < 4; ++df) acc[df] *= alpha;
    }

    float rs0 = 0.f, rs1 = 0.f, rs2 = 0.f, rs3 = 0.f;
#pragma unroll
    for (int j = 0; j < 8; ++j) { pf[j]    = __expf(pf[j]    - m_run); rs0 += pf[j]; }
#pragma unroll
    for (int j = 8; j < 16; ++j){ pf[j]    = __expf(pf[j]    - m_run); rs1 += pf[j]; }
#pragma unroll
    for (int j = 0; j < 8; ++j) { pf[16+j] = __expf(pf[16+j] - m_run); rs2 += pf[16+j]; }
#pragma unroll
    for (int j = 8; j < 16; ++j){ pf[16+j] = __expf(pf[16+j] - m_run); rs3 += pf[16+j]; }
    float rs = (rs0 + rs1) + (rs2 + rs3);
    rs += __shfl_xor(rs, 32, 64);
    l_run += rs;

    unsigned int pb[2][8];
#pragma unroll
    for (int f = 0; f < 2; ++f) {
#pragma unroll
      for (int u = 0; u < 4; ++u) {
        pb[f][2*u]   = cvtpk(pf[f*16 + 4*u + 0], pf[f*16 + 4*u + 1]);
        pb[f][2*u+1] = cvtpk(pf[f*16 + 4*u + 2], pf[f*16 + 4*u + 3]);
      }
      plswap(pb[f][0], pb[f][2]);
      plswap(pb[f][1], pb[f][3]);
      plswap(pb[f][4], pb[f][6]);
      plswap(pb[f][5], pb[f][7]);
    }

#pragma unroll
    for (int s = 0; s < 4; ++s) {
      union { unsigned int u[4]; bf16x8 v; } pbv;
#pragma unroll
      for (int u = 0; u < 4; ++u) pbv.u[u] = pb[s >> 1][(s & 1) * 4 + u];
#pragma unroll
      for (int df = 0; df < 4; ++df) {
        bf16x8 vb = *(const bf16x8*)(VtG + (df*32 + l31) * 72 + s*16 + hi*8);
        __builtin_amdgcn_s_setprio(1);
        acc[df] = __builtin_amdgcn_mfma_f32_32x32x16_bf16(vb, pbv.v, acc[df], 0, 0, 0);
        __builtin_amdgcn_s_setprio(0);
      }
    }

    __syncthreads();   // reads of buf p done; writes to buf p^1 visible
  }

  // ---- split-K combine ----
  float* EXf = (float*)SH;                       // [4][64][68] f32 (69632 B)
  float* MLf = (float*)(SH + 35840);             // byte 71680: [4][64][2] f32
  if (gid == 1) {
    MLf[(wq*64 + l)*2 + 0] = m_run;
    MLf[(wq*64 + l)*2 + 1] = l_run;
#pragma unroll
    for (int df = 0; df < 4; ++df)
#pragma unroll
      for (int u = 0; u < 4; ++u) {
        f32x4 ch = {acc[df][4*u], acc[df][4*u+1], acc[df][4*u+2], acc[df][4*u+3]};
        *(f32x4*)&EXf[(wq*64 + l)*68 + df*16 + u*4] = ch;
      }
  }
  __syncthreads();
  if (gid == 0) {
    float mB = MLf[(wq*64 + l)*2 + 0];
    float lB = MLf[(wq*64 + l)*2 + 1];
    float mF = fmaxf(m_run, mB);
    float a0 = __expf(m_run - mF), a1 = __expf(mB - mF);
    float inv = 1.0f / (l_run * a0 + lB * a1);
    a0 *= inv; a1 *= inv;
#pragma unroll
    for (int df = 0; df < 4; ++df)
#pragma unroll
      for (int u = 0; u < 4; ++u) {
        f32x4 cb = *(const f32x4*)&EXf[(wq*64 + l)*68 + df*16 + u*4];
#pragma unroll
        for (int e = 0; e < 4; ++e)
          acc[df][4*u+e] = acc[df][4*u+e] * a0 + cb[e] * a1;
      }
  }
  __syncthreads();

  // ---- transpose epilogue ----
  unsigned int* OT = (unsigned int*)SH;
  if (gid == 0) {
#pragma unroll
    for (int df = 0; df < 4; ++df)
#pragma unroll
      for (int u = 0; u < 4; ++u) {
        unsigned int d0 = cvtpk(acc[df][4*u+0], acc[df][4*u+1]);
        unsigned int d1 = cvtpk(acc[df][4*u+2], acc[df][4*u+3]);
        uint2 dd; dd.x = d0; dd.y = d1;
        *(uint2*)&OT[(wq*32 + l31)*68 + df*16 + 2*hi + 4*u] = dd;
      }
  }
  __syncthreads();
  {
    const int q = t >> 2, sg = t & 3;
    size_t rowbase = ((size_t)b * TSEQ + q0 + q) * DMODEL + MODE * 512 + h * HDIM;
#pragma unroll
    for (int u = 0; u < 4; ++u) {
      bf16x8 vv = *(const bf16x8*)&OT[q*68 + u*16 + sg*4];
      *(bf16x8*)(AO + rowbase + (u*16 + sg*4)*2) = vv;
    }
  }
}

// grid (16, 8, 2): z=0 -> causal+anti-causal fused, z=1 -> bidirectional.
__global__ __launch_bounds__(512, 2) void k_attn(
    const unsigned short* __restrict__ Q, const unsigned short* __restrict__ K,
    const unsigned short* __restrict__ VT, unsigned short* __restrict__ AO)
{
  __shared__ __align__(16) unsigned short SH[71680];   // 143,360 B (dbuf K/V)

  const int qt = blockIdx.x;
  const int bh = blockIdx.y;
  if (blockIdx.z == 0) {
    flash_phase<0>(qt, bh, Q, K, VT, AO, SH);
    flash_phase<1>(qt, bh, Q, K, VT, AO, SH);
  } else {
    flash_phase<2>(qt, bh, Q, K, VT, AO, SH);
  }
}

// ---------------------------------------------------------------------------
extern "C" void kernel_launch(void* const* d_in, const int* in_sizes, int n_in,
                              void* d_out, int out_size, void* d_ws, size_t ws_size,
                              hipStream_t stream)
{
  (void)in_sizes; (void)n_in; (void)out_size; (void)ws_size;
  const float* Xf  = (const float*)d_in[0];
  const float* WOf = (const float*)d_in[10];
  const float* qw  = (const float*)d_in[11];
  const float* kw  = (const float*)d_in[12];

  const size_t S = (size_t)NBR * 2 * NHB * TSEQ * HDIM;       // 6,291,456 elems
  unsigned short* Qs   = (unsigned short*)d_ws;                // S
  unsigned short* Ks   = Qs + S;                               // S
  unsigned short* Vs   = Ks + S;                               // S
  unsigned short* AO   = Vs + S;                               // S
  unsigned short* Xbf  = AO + S;                               // S (= MROWS*DMODEL)
  unsigned short* Wbf  = Xbf + (size_t)MROWS * DMODEL;         // 9*512*1536
  unsigned short* WObf = Wbf + (size_t)9 * 512 * DMODEL;       // 1536*1536
  unsigned short* VTs  = Xbf;   // reuse: Xbf dead after k_gemm8<0>
  float* Cout = (float*)d_out;

  dim3 blk(256);

  k_cvt<<<dim3((MROWS * DMODEL) / 1024), blk, 0, stream>>>(Xf, Xbf, (MROWS * DMODEL) / 4);
  W9 w9;
  for (int i = 0; i < 9; ++i) w9.w[i] = (const float*)d_in[1 + i];
  k_cvt9<<<dim3((512 * DMODEL) / 1024, 9), blk, 0, stream>>>(w9, Wbf, (512 * DMODEL) / 4);
  k_cvt<<<dim3((DMODEL * DMODEL) / 1024), blk, 0, stream>>>(WOf, WObf, (DMODEL * DMODEL) / 4);

  // fused QKV projection: [4096, 4608] = X @ Wall^T, grid 768 = 3*256
  k_gemm8<0><<<dim3(32, 24), dim3(512), 0, stream>>>(Xbf, Wbf, Qs, Ks, Vs, nullptr);
  k_rope<<<dim3(12288), blk, 0, stream>>>(Qs, Ks, qw, kw);
  k_vtrans<<<dim3(32, 2, 24), blk, 0, stream>>>(Vs, VTs);
  k_attn<<<dim3(16, 8, 2), dim3(512), 0, stream>>>(Qs, Ks, VTs, AO);
  // output projection: [4096, 1536] = AO @ wo^T, grid 256
  k_gemm8<1><<<dim3(32, 8), dim3(512), 0, stream>>>(AO, WObf, nullptr, nullptr, nullptr, Cout);
}

// Round 15
// 183.867 us; speedup vs baseline: 1.0623x; 1.0623x over previous
//
#include <hip/hip_runtime.h>
#include <stdint.h>
#include <stddef.h>

typedef __attribute__((ext_vector_type(8))) short bf16x8;
typedef __attribute__((ext_vector_type(4))) float f32x4;
typedef __attribute__((ext_vector_type(16))) float f32x16;

#define DMODEL 1536
#define TSEQ   2048
#define HDIM   128
#define NBR    3
#define NHB    4      // heads per branch
#define MROWS  4096   // B*T

__device__ __forceinline__ float bf2f(unsigned short u) {
  union { unsigned int i; float f; } v; v.i = ((unsigned int)u) << 16; return v.f;
}
__device__ __forceinline__ unsigned short f2bf(float f) {
  union { float f; unsigned int i; } v; v.f = f;
  unsigned int r = v.i + 0x7fffu + ((v.i >> 16) & 1u);
  return (unsigned short)(r >> 16);
}
__device__ __forceinline__ unsigned int cvtpk(float lo, float hi) {
  unsigned int r;
  asm("v_cvt_pk_bf16_f32 %0, %1, %2" : "=v"(r) : "v"(lo), "v"(hi));
  return r;
}
__device__ __forceinline__ void plswap(unsigned int& a, unsigned int& b) {
  asm("v_permlane32_swap_b32 %0, %1" : "+v"(a), "+v"(b));
}
__device__ __forceinline__ void gload_lds16(const void* g, void* l) {
  __builtin_amdgcn_global_load_lds((__attribute__((address_space(1))) void*)g,
                                   (__attribute__((address_space(3))) void*)l,
                                   16, 0, 0);
}

// ---------------------------------------------------------------------------
// f32 -> bf16 conversion kernels (pre-pass)
// ---------------------------------------------------------------------------
__global__ __launch_bounds__(256) void k_cvt(const float* __restrict__ src,
                                             unsigned short* __restrict__ dst,
                                             int n4) {
  int i = blockIdx.x * 256 + threadIdx.x;
  if (i >= n4) return;
  float4 v = ((const float4*)src)[i];
  ushort4 o;
  o.x = f2bf(v.x); o.y = f2bf(v.y); o.z = f2bf(v.z); o.w = f2bf(v.w);
  ((ushort4*)dst)[i] = o;
}

struct W9 { const float* w[9]; };

__global__ __launch_bounds__(256) void k_cvt9(W9 ws, unsigned short* __restrict__ dst,
                                              int n4) {
  int seg = blockIdx.y;
  const float* __restrict__ src = ws.w[seg];
  unsigned short* __restrict__ d = dst + (size_t)seg * (size_t)n4 * 4;
  int i = blockIdx.x * 256 + threadIdx.x;
  if (i >= n4) return;
  float4 v = ((const float4*)src)[i];
  ushort4 o;
  o.x = f2bf(v.x); o.y = f2bf(v.y); o.z = f2bf(v.z); o.w = f2bf(v.w);
  ((ushort4*)d)[i] = o;
}

// ---------------------------------------------------------------------------
// Pipelined GEMM (R8/R13 config — 69 us / 833 TF / 0 conflicts):
// C = A[4096,1536] * B[N,1536]^T, bf16, tile 128x192x64, 8 waves (2Mx4N).
// A and B both via global_load_lds + XOR swizzle; counted s_waitcnt vmcnt(5).
// R15: V written TRANSPOSED via LDS round-trip in the epilogue (k_vtrans
// eliminated). V frags -> LT[192][132] (stride 132 => 8B-aligned ushort4,
// 2-bank stride = free), barrier, coalesced b128 V^T stores (256B segments,
// no write amplification — the R9 strided-store disaster is avoided by
// transposing through LDS).
// ---------------------------------------------------------------------------
#define GBM 128
#define GBN 192
#define GBK 64
#define GK  1536
#define GNT (GK / GBK)   // 24 K-tiles

template<int EPI>
__global__ __launch_bounds__(512, 4) void k_gemm8(
    const unsigned short* __restrict__ A, const unsigned short* __restrict__ Bw,
    unsigned short* __restrict__ Qs, unsigned short* __restrict__ Ksl,
    unsigned short* __restrict__ Vs, float* __restrict__ Cout)
{
  __shared__ __align__(16) unsigned short POOL[40960];   // 80 KiB
  unsigned short* As = POOL;            // 2*128*64 = 16384 u16
  unsigned short* Bs = POOL + 16384;    // 2*192*64 = 24576 u16
  unsigned short* LT = POOL;            // epilogue alias: [192][132] u16

  const int t = threadIdx.x, ln = t & 63, w = t >> 6;
  const int wm = w >> 2, wn = w & 3, g = ln >> 4, li = ln & 15;

  const int nwg = gridDim.x * gridDim.y;
  const int lid = blockIdx.y * gridDim.x + blockIdx.x;
  const int s = (lid & 7) * (nwg >> 3) + (lid >> 3);
  const int m0 = (s & 31) * GBM;
  const int n0 = (s >> 5) * GBN;

  f32x4 zero4 = {0.f, 0.f, 0.f, 0.f};
  f32x4 acc[4][3];
#pragma unroll
  for (int i = 0; i < 4; ++i)
#pragma unroll
    for (int j = 0; j < 3; ++j) acc[i][j] = zero4;

  auto STAGE = [&](int p, int kt) {
    const unsigned short* Ag = A + (size_t)m0 * GK + kt * GBK;
    unsigned short* Al = As + p * (GBM * GBK);
#pragma unroll
    for (int i = 0; i < 2; ++i) {
      int ch = i * 512 + t; int r = ch >> 3, c = ch & 7;
      gload_lds16(Ag + (size_t)r * GK + ((c ^ (r & 7)) * 8), Al + ch * 8);
    }
    const unsigned short* Bg = Bw + (size_t)n0 * GK + kt * GBK;
    unsigned short* Bl = Bs + p * (GBN * GBK);
#pragma unroll
    for (int i = 0; i < 3; ++i) {
      int ch = i * 512 + t; int r = ch >> 3, c = ch & 7;
      gload_lds16(Bg + (size_t)r * GK + ((c ^ (r & 7)) * 8), Bl + ch * 8);
    }
  };

  STAGE(0, 0);
  STAGE(1, 1);

  for (int kt = 0; kt < GNT; ++kt) {
    const int cur = kt & 1;
    if (kt < GNT - 1) { asm volatile("s_waitcnt vmcnt(5)" ::: "memory"); }
    else              { asm volatile("s_waitcnt vmcnt(0)" ::: "memory"); }
    __builtin_amdgcn_sched_barrier(0);
    __builtin_amdgcn_s_barrier();
    __builtin_amdgcn_sched_barrier(0);
    asm volatile("" ::: "memory");

    const unsigned short* Al = As + cur * (GBM * GBK);
    const unsigned short* Bl = Bs + cur * (GBN * GBK);
#pragma unroll
    for (int kh = 0; kh < 2; ++kh) {
      bf16x8 af[4], bfn[3];
#pragma unroll
      for (int mf = 0; mf < 4; ++mf) {
        int r = wm * 64 + mf * 16 + li;
        af[mf] = *(const bf16x8*)(Al + r * 64 + (((kh * 4 + g) ^ (li & 7)) * 8));
      }
#pragma unroll
      for (int nf = 0; nf < 3; ++nf) {
        int r = wn * 48 + nf * 16 + li;
        bfn[nf] = *(const bf16x8*)(Bl + r * 64 + (((kh * 4 + g) ^ (li & 7)) * 8));
      }
      __builtin_amdgcn_s_setprio(1);
#pragma unroll
      for (int mf = 0; mf < 4; ++mf)
#pragma unroll
        for (int nf = 0; nf < 3; ++nf)
          acc[mf][nf] = __builtin_amdgcn_mfma_f32_16x16x32_bf16(
              af[mf], bfn[nf], acc[mf][nf], 0, 0, 0);
      __builtin_amdgcn_s_setprio(0);
    }
    asm volatile("" ::: "memory");
    __builtin_amdgcn_sched_barrier(0);
    __builtin_amdgcn_s_barrier();
    __builtin_amdgcn_sched_barrier(0);
    if (kt + 2 < GNT) STAGE(cur, kt + 2);
  }

  // ---- epilogue pass 1: Q/K scalar stores (coalesced cols) + V -> LT ----
  bool hasV = false;
  if (EPI == 0) {
    int matA = n0 >> 9, matB = (n0 + GBN - 1) >> 9;
    hasV = ((matA % 3) == 2) || ((matB % 3) == 2);
  }

#pragma unroll
  for (int mf = 0; mf < 4; ++mf)
#pragma unroll
    for (int nf = 0; nf < 3; ++nf) {
      int row0 = wm * 64 + mf * 16 + g * 4;   // tile row 0..127 (mult of 4)
      int colL = wn * 48 + nf * 16 + li;      // tile col 0..191
      int col  = n0 + colL;
      if (EPI == 0) {
        int mat = col >> 9, qkv = mat % 3;    // uniform within frag
        if (qkv == 2) {
          ushort4 o;
          o.x = f2bf(acc[mf][nf][0]); o.y = f2bf(acc[mf][nf][1]);
          o.z = f2bf(acc[mf][nf][2]); o.w = f2bf(acc[mf][nf][3]);
          *(ushort4*)(LT + colL * 132 + row0) = o;
        } else {
          int br = mat / 3;
          int within = col & 511;
          int h = within >> 7, d = within & 127;
          unsigned short* dst = (qkv == 0) ? Qs : Ksl;
#pragma unroll
          for (int rr = 0; rr < 4; ++rr) {
            int row = m0 + row0 + rr;
            int b = row >> 11, tt = row & 2047;
            dst[((size_t)((br * 2 + b) * 4 + h) * TSEQ + tt) * HDIM + d] =
                f2bf(acc[mf][nf][rr]);
          }
        }
      } else {
#pragma unroll
        for (int rr = 0; rr < 4; ++rr)
          Cout[(size_t)(m0 + row0 + rr) * DMODEL + col] = acc[mf][nf][rr];
      }
    }

  // ---- epilogue pass 2: LT -> coalesced V^T stores ----
  if (EPI == 0 && hasV) {
    __syncthreads();
    const int bx = m0 >> 11, tb0 = m0 & 2047;
#pragma unroll
    for (int j = 0; j < 6; ++j) {
      int ch = j * 512 + t;            // 0..3071 = 192 cols x 16 t-chunks
      int ci = ch >> 4;
      int col = n0 + ci;
      int mat = col >> 9;
      if (mat % 3 == 2) {
        int within = col & 511;
        int hh = within >> 7, dd = within & 127;
        int brx = mat / 3;
        int t0c = (ch & 15) * 8;
        ushort4 lo  = *(const ushort4*)(LT + ci * 132 + t0c);
        ushort4 hi4 = *(const ushort4*)(LT + ci * 132 + t0c + 4);
        union { ushort4 a[2]; bf16x8 v; } u;
        u.a[0] = lo; u.a[1] = hi4;
        *(bf16x8*)(Vs + (size_t)((brx * 2 + bx) * 4 + hh) * (TSEQ * HDIM)
                      + (size_t)dd * TSEQ + tb0 + t0c) = u.v;
      }
    }
  }
}

// ---------------------------------------------------------------------------
// RMSNorm + RoPE in place on Q,K slabs (bf16). One wave per row.
// ---------------------------------------------------------------------------
__global__ __launch_bounds__(256) void k_rope(
    unsigned short* __restrict__ Q, unsigned short* __restrict__ K,
    const float* __restrict__ qw, const float* __restrict__ kw)
{
  const int t = threadIdx.x, ln = t & 63, w = t >> 6;
  const int rid = blockIdx.x * 4 + w;          // 0..49151
  const int tt  = rid & (TSEQ - 1);
  const size_t base = (size_t)rid * HDIM;

  const float ang = (float)tt * exp2f(-0.31143075464f * (float)ln);
  float s, c;
  sincosf(ang, &s, &c);

#pragma unroll
  for (int which = 0; which < 2; ++which) {
    unsigned short* P = which ? K : Q;
    const float* Wn = which ? kw : qw;
    float x1 = bf2f(P[base + ln]);
    float x2 = bf2f(P[base + 64 + ln]);
    float ss = x1 * x1 + x2 * x2;
#pragma unroll
    for (int off = 1; off < 64; off <<= 1) ss += __shfl_xor(ss, off, 64);
    float rr = rsqrtf(ss * (1.0f / 128.0f) + 1.1920928955078125e-07f);
    float y1 = x1 * rr * Wn[ln];
    float y2 = x2 * rr * Wn[64 + ln];
    P[base + ln]      = f2bf(y1 * c - y2 * s);
    P[base + 64 + ln] = f2bf(y2 * c + y1 * s);
  }
}

// ---------------------------------------------------------------------------
// Flash attention (R13 structure: single-buffer K/V, 73.7 KB -> 2 blocks/CU;
// R14's dbuf halved occupancy and was net-negative).
// 32x32x16 MFMA + split-K groups + in-register P.
// R15: T13 defer-max — rescale only when m - m_run > 8 (P bounded by e^8).
// ---------------------------------------------------------------------------
#define ATT_SCALE 0.08838834764831845f

template<int MODE>
__device__ __forceinline__ void flash_phase(
    int qt, int bh,
    const unsigned short* __restrict__ Q, const unsigned short* __restrict__ K,
    const unsigned short* __restrict__ VT, unsigned short* __restrict__ AO,
    unsigned short* SH)
{
  const int b = bh >> 2, h = bh & 3;
  const int t = threadIdx.x, l = t & 63, w = t >> 6;
  const int hi = l >> 5, l31 = l & 31;
  const int wq = w & 3, gid = w >> 2;
  const size_t slab = (size_t)(MODE * 8 + bh) * (TSEQ * HDIM);
  const int q0 = qt * 128;

  unsigned short* KsG = SH + gid * 17920;        // [64][136] u16
  unsigned short* VtG = KsG + 8704;              // [128][72] u16

  bf16x8 qf[8];
  {
    const unsigned short* qp = Q + slab + (size_t)(q0 + wq*32 + l31) * HDIM + hi*8;
#pragma unroll
    for (int st = 0; st < 8; ++st) qf[st] = *(const bf16x8*)(qp + st*16);
  }

  f32x16 zero16;
#pragma unroll
  for (int e = 0; e < 16; ++e) zero16[e] = 0.f;
  f32x16 acc[4];
#pragma unroll
  for (int df = 0; df < 4; ++df) acc[df] = zero16;
  float m_run = -1e30f, l_run = 0.f;

  int n, ktbase, diagAt;
  if (MODE == 0)      { n = qt + 1;  ktbase = gid;          diagAt = n - 1; }
  else if (MODE == 1) { n = 16 - qt; ktbase = 2*qt + gid;   diagAt = 0; }
  else                { n = 16;      ktbase = gid;          diagAt = -1; }

  const int tl = t & 255;
  bf16x8 rk[4], rv[4];
  auto LOADT = [&](int kt) {
    const int k0 = kt * 64;
#pragma unroll
    for (int j = 0; j < 4; ++j) {
      int c = j * 256 + tl;
      rk[j] = *(const bf16x8*)(K  + slab + (size_t)(k0 + (c >> 4)) * HDIM + (c & 15) * 8);
      rv[j] = *(const bf16x8*)(VT + slab + (size_t)(c >> 3) * TSEQ + k0 + (c & 7) * 8);
    }
  };

  LOADT(ktbase);

  for (int i = 0; i < n; ++i) {
    const int kt = ktbase + 2 * i;
    const int k0 = kt * 64;
    __syncthreads();
#pragma unroll
    for (int j = 0; j < 4; ++j) {
      int c = j * 256 + tl;
      *(bf16x8*)(KsG + (c >> 4) * 136 + (c & 15) * 8) = rk[j];
      *(bf16x8*)(VtG + (c >> 3) * 72  + (c & 7) * 8)  = rv[j];
    }
    if (i + 1 < n) LOADT(kt + 2);
    __syncthreads();

    f32x16 sf0 = zero16, sf1 = zero16;
#pragma unroll
    for (int st = 0; st < 8; ++st) {
      bf16x8 kf0 = *(const bf16x8*)(KsG + l31 * 136 + st*16 + hi*8);
      bf16x8 kf1 = *(const bf16x8*)(KsG + (32 + l31) * 136 + st*16 + hi*8);
      __builtin_amdgcn_s_setprio(1);
      sf0 = __builtin_amdgcn_mfma_f32_32x32x16_bf16(kf0, qf[st], sf0, 0, 0, 0);
      sf1 = __builtin_amdgcn_mfma_f32_32x32x16_bf16(kf1, qf[st], sf1, 0, 0, 0);
      __builtin_amdgcn_s_setprio(0);
    }

    float pf[32];
#pragma unroll
    for (int r = 0; r < 16; ++r) { pf[r] = sf0[r] * ATT_SCALE; pf[16+r] = sf1[r] * ATT_SCALE; }

    if (MODE != 2 && i == diagAt) {
      const int qg = q0 + wq*32 + l31;
#pragma unroll
      for (int f = 0; f < 2; ++f)
#pragma unroll
        for (int r = 0; r < 16; ++r) {
          int kg = k0 + f*32 + 4*hi + (r & 3) + 8*(r >> 2);
          bool ok = (MODE == 0) ? (kg <= qg) : (kg >= qg);
          if (!ok) pf[f*16 + r] = -1e30f;
        }
    }

    float m = pf[0];
#pragma unroll
    for (int j = 1; j < 32; ++j) m = fmaxf(m, pf[j]);
    m = fmaxf(m, __shfl_xor(m, 32, 64));

    // T13 defer-max: rescale only when max grew by > 8 (P bounded by e^8)
    if (__any(m - m_run > 8.0f)) {
      float mn = fmaxf(m_run, m);
      float alpha = __expf(m_run - mn);
      m_run = mn;
      l_run *= alpha;
#pragma unroll
      for (int df = 0; df < 4; ++df) acc[df] *= alpha;
    }

    float rs0 = 0.f, rs1 = 0.f, rs2 = 0.f, rs3 = 0.f;
#pragma unroll
    for (int j = 0; j < 8; ++j) { pf[j]    = __expf(pf[j]    - m_run); rs0 += pf[j]; }
#pragma unroll
    for (int j = 8; j < 16; ++j){ pf[j]    = __expf(pf[j]    - m_run); rs1 += pf[j]; }
#pragma unroll
    for (int j = 0; j < 8; ++j) { pf[16+j] = __expf(pf[16+j] - m_run); rs2 += pf[16+j]; }
#pragma unroll
    for (int j = 8; j < 16; ++j){ pf[16+j] = __expf(pf[16+j] - m_run); rs3 += pf[16+j]; }
    float rs = (rs0 + rs1) + (rs2 + rs3);
    rs += __shfl_xor(rs, 32, 64);
    l_run += rs;

    unsigned int pb[2][8];
#pragma unroll
    for (int f = 0; f < 2; ++f) {
#pragma unroll
      for (int u = 0; u < 4; ++u) {
        pb[f][2*u]   = cvtpk(pf[f*16 + 4*u + 0], pf[f*16 + 4*u + 1]);
        pb[f][2*u+1] = cvtpk(pf[f*16 + 4*u + 2], pf[f*16 + 4*u + 3]);
      }
      plswap(pb[f][0], pb[f][2]);
      plswap(pb[f][1], pb[f][3]);
      plswap(pb[f][4], pb[f][6]);
      plswap(pb[f][5], pb[f][7]);
    }

#pragma unroll
    for (int s = 0; s < 4; ++s) {
      union { unsigned int u[4]; bf16x8 v; } pbv;
#pragma unroll
      for (int u = 0; u < 4; ++u) pbv.u[u] = pb[s >> 1][(s & 1) * 4 + u];
#pragma unroll
      for (int df = 0; df < 4; ++df) {
        bf16x8 vb = *(const bf16x8*)(VtG + (df*32 + l31) * 72 + s*16 + hi*8);
        __builtin_amdgcn_s_setprio(1);
        acc[df] = __builtin_amdgcn_mfma_f32_32x32x16_bf16(vb, pbv.v, acc[df], 0, 0, 0);
        __builtin_amdgcn_s_setprio(0);
      }
    }
  }

  // ---- split-K combine ----
  __syncthreads();
  float* EXf = (float*)SH;                       // [4][64][68] f32
  float* MLf = (float*)(SH + 35840);             // [4][64][2]  f32
  if (gid == 1) {
    MLf[(wq*64 + l)*2 + 0] = m_run;
    MLf[(wq*64 + l)*2 + 1] = l_run;
#pragma unroll
    for (int df = 0; df < 4; ++df)
#pragma unroll
      for (int u = 0; u < 4; ++u) {
        f32x4 ch = {acc[df][4*u], acc[df][4*u+1], acc[df][4*u+2], acc[df][4*u+3]};
        *(f32x4*)&EXf[(wq*64 + l)*68 + df*16 + u*4] = ch;
      }
  }
  __syncthreads();
  if (gid == 0) {
    float mB = MLf[(wq*64 + l)*2 + 0];
    float lB = MLf[(wq*64 + l)*2 + 1];
    float mF = fmaxf(m_run, mB);
    float a0 = __expf(m_run - mF), a1 = __expf(mB - mF);
    float inv = 1.0f / (l_run * a0 + lB * a1);
    a0 *= inv; a1 *= inv;
#pragma unroll
    for (int df = 0; df < 4; ++df)
#pragma unroll
      for (int u = 0; u < 4; ++u) {
        f32x4 cb = *(const f32x4*)&EXf[(wq*64 + l)*68 + df*16 + u*4];
#pragma unroll
        for (int e = 0; e < 4; ++e)
          acc[df][4*u+e] = acc[df][4*u+e] * a0 + cb[e] * a1;
      }
  }
  __syncthreads();

  // ---- transpose epilogue ----
  unsigned int* OT = (unsigned int*)SH;
  if (gid == 0) {
#pragma unroll
    for (int df = 0; df < 4; ++df)
#pragma unroll
      for (int u = 0; u < 4; ++u) {
        unsigned int d0 = cvtpk(acc[df][4*u+0], acc[df][4*u+1]);
        unsigned int d1 = cvtpk(acc[df][4*u+2], acc[df][4*u+3]);
        uint2 dd; dd.x = d0; dd.y = d1;
        *(uint2*)&OT[(wq*32 + l31)*68 + df*16 + 2*hi + 4*u] = dd;
      }
  }
  __syncthreads();
  {
    const int q = t >> 2, sg = t & 3;
    size_t rowbase = ((size_t)b * TSEQ + q0 + q) * DMODEL + MODE * 512 + h * HDIM;
#pragma unroll
    for (int u = 0; u < 4; ++u) {
      bf16x8 vv = *(const bf16x8*)&OT[q*68 + u*16 + sg*4];
      *(bf16x8*)(AO + rowbase + (u*16 + sg*4)*2) = vv;
    }
  }
}

// grid (16, 8, 2): z=0 -> causal+anti-causal fused, z=1 -> bidirectional.
__global__ __launch_bounds__(512, 2) void k_attn(
    const unsigned short* __restrict__ Q, const unsigned short* __restrict__ K,
    const unsigned short* __restrict__ VT, unsigned short* __restrict__ AO)
{
  __shared__ __align__(16) unsigned short SH[36864];   // 73,728 B

  const int qt = blockIdx.x;
  const int bh = blockIdx.y;
  if (blockIdx.z == 0) {
    flash_phase<0>(qt, bh, Q, K, VT, AO, SH);
    flash_phase<1>(qt, bh, Q, K, VT, AO, SH);
  } else {
    flash_phase<2>(qt, bh, Q, K, VT, AO, SH);
  }
}

// ---------------------------------------------------------------------------
extern "C" void kernel_launch(void* const* d_in, const int* in_sizes, int n_in,
                              void* d_out, int out_size, void* d_ws, size_t ws_size,
                              hipStream_t stream)
{
  (void)in_sizes; (void)n_in; (void)out_size; (void)ws_size;
  const float* Xf  = (const float*)d_in[0];
  const float* WOf = (const float*)d_in[10];
  const float* qw  = (const float*)d_in[11];
  const float* kw  = (const float*)d_in[12];

  const size_t S = (size_t)NBR * 2 * NHB * TSEQ * HDIM;       // 6,291,456 elems
  unsigned short* Qs   = (unsigned short*)d_ws;                // S
  unsigned short* Ks   = Qs + S;                               // S
  unsigned short* Vs   = Ks + S;                               // S (holds V^T)
  unsigned short* AO   = Vs + S;                               // S
  unsigned short* Xbf  = AO + S;                               // S (= MROWS*DMODEL)
  unsigned short* Wbf  = Xbf + (size_t)MROWS * DMODEL;         // 9*512*1536
  unsigned short* WObf = Wbf + (size_t)9 * 512 * DMODEL;       // 1536*1536
  float* Cout = (float*)d_out;

  dim3 blk(256);

  k_cvt<<<dim3((MROWS * DMODEL) / 1024), blk, 0, stream>>>(Xf, Xbf, (MROWS * DMODEL) / 4);
  W9 w9;
  for (int i = 0; i < 9; ++i) w9.w[i] = (const float*)d_in[1 + i];
  k_cvt9<<<dim3((512 * DMODEL) / 1024, 9), blk, 0, stream>>>(w9, Wbf, (512 * DMODEL) / 4);
  k_cvt<<<dim3((DMODEL * DMODEL) / 1024), blk, 0, stream>>>(WOf, WObf, (DMODEL * DMODEL) / 4);

  // fused QKV projection: [4096, 4608] = X @ Wall^T (V written as V^T)
  k_gemm8<0><<<dim3(32, 24), dim3(512), 0, stream>>>(Xbf, Wbf, Qs, Ks, Vs, nullptr);
  k_rope<<<dim3(12288), blk, 0, stream>>>(Qs, Ks, qw, kw);
  k_attn<<<dim3(16, 8, 2), dim3(512), 0, stream>>>(Qs, Ks, Vs, AO);
  // output projection: [4096, 1536] = AO @ wo^T
  k_gemm8<1><<<dim3(32, 8), dim3(512), 0, stream>>>(AO, WObf, nullptr, nullptr, nullptr, Cout);
}

// Round 16
// 177.746 us; speedup vs baseline: 1.0989x; 1.0344x over previous
//
#include <hip/hip_runtime.h>
#include <stdint.h>
#include <stddef.h>

typedef __attribute__((ext_vector_type(8))) short bf16x8;
typedef __attribute__((ext_vector_type(4))) float f32x4;
typedef __attribute__((ext_vector_type(16))) float f32x16;

#define DMODEL 1536
#define TSEQ   2048
#define HDIM   128
#define NBR    3
#define NHB    4      // heads per branch
#define MROWS  4096   // B*T

__device__ __forceinline__ float bf2f(unsigned short u) {
  union { unsigned int i; float f; } v; v.i = ((unsigned int)u) << 16; return v.f;
}
__device__ __forceinline__ unsigned short f2bf(float f) {
  union { float f; unsigned int i; } v; v.f = f;
  unsigned int r = v.i + 0x7fffu + ((v.i >> 16) & 1u);
  return (unsigned short)(r >> 16);
}
__device__ __forceinline__ unsigned int cvtpk(float lo, float hi) {
  unsigned int r;
  asm("v_cvt_pk_bf16_f32 %0, %1, %2" : "=v"(r) : "v"(lo), "v"(hi));
  return r;
}
__device__ __forceinline__ void plswap(unsigned int& a, unsigned int& b) {
  asm("v_permlane32_swap_b32 %0, %1" : "+v"(a), "+v"(b));
}
__device__ __forceinline__ void gload_lds16(const void* g, void* l) {
  __builtin_amdgcn_global_load_lds((__attribute__((address_space(1))) void*)g,
                                   (__attribute__((address_space(3))) void*)l,
                                   16, 0, 0);
}

// ---------------------------------------------------------------------------
// Fused f32 -> bf16 conversion: X (6144 blks) | 9 weights (6912) | WO (2304)
// ---------------------------------------------------------------------------
struct CVT { const float* s[11]; };

__global__ __launch_bounds__(256) void k_cvt_all(
    CVT cv, unsigned short* __restrict__ Xbf, unsigned short* __restrict__ Wbf,
    unsigned short* __restrict__ WObf)
{
  const int bid = blockIdx.x;
  const float* __restrict__ src;
  unsigned short* __restrict__ dst;
  int i4;
  if (bid < 6144) {
    src = cv.s[0]; dst = Xbf; i4 = bid * 256 + threadIdx.x;
  } else if (bid < 13056) {
    int r = bid - 6144; int seg = r / 768; int inner = r - seg * 768;
    src = cv.s[1 + seg]; dst = Wbf + (size_t)seg * 786432;
    i4 = inner * 256 + threadIdx.x;
  } else {
    int r = bid - 13056; src = cv.s[10]; dst = WObf;
    i4 = r * 256 + threadIdx.x;
  }
  float4 v = ((const float4*)src)[i4];
  ushort4 o;
  o.x = f2bf(v.x); o.y = f2bf(v.y); o.z = f2bf(v.z); o.w = f2bf(v.w);
  ((ushort4*)dst)[i4] = o;
}

// ---------------------------------------------------------------------------
// Pipelined GEMM (R8/R13 config): tile 128x192x64, 8 waves, vmcnt(5).
// R15: V written TRANSPOSED via LDS round-trip in the epilogue.
// ---------------------------------------------------------------------------
#define GBM 128
#define GBN 192
#define GBK 64
#define GK  1536
#define GNT (GK / GBK)   // 24 K-tiles

template<int EPI>
__global__ __launch_bounds__(512, 4) void k_gemm8(
    const unsigned short* __restrict__ A, const unsigned short* __restrict__ Bw,
    unsigned short* __restrict__ Qs, unsigned short* __restrict__ Ksl,
    unsigned short* __restrict__ Vs, float* __restrict__ Cout)
{
  __shared__ __align__(16) unsigned short POOL[40960];   // 80 KiB
  unsigned short* As = POOL;            // 2*128*64 = 16384 u16
  unsigned short* Bs = POOL + 16384;    // 2*192*64 = 24576 u16
  unsigned short* LT = POOL;            // epilogue alias: [192][132] u16

  const int t = threadIdx.x, ln = t & 63, w = t >> 6;
  const int wm = w >> 2, wn = w & 3, g = ln >> 4, li = ln & 15;

  const int nwg = gridDim.x * gridDim.y;
  const int lid = blockIdx.y * gridDim.x + blockIdx.x;
  const int s = (lid & 7) * (nwg >> 3) + (lid >> 3);
  const int m0 = (s & 31) * GBM;
  const int n0 = (s >> 5) * GBN;

  f32x4 zero4 = {0.f, 0.f, 0.f, 0.f};
  f32x4 acc[4][3];
#pragma unroll
  for (int i = 0; i < 4; ++i)
#pragma unroll
    for (int j = 0; j < 3; ++j) acc[i][j] = zero4;

  auto STAGE = [&](int p, int kt) {
    const unsigned short* Ag = A + (size_t)m0 * GK + kt * GBK;
    unsigned short* Al = As + p * (GBM * GBK);
#pragma unroll
    for (int i = 0; i < 2; ++i) {
      int ch = i * 512 + t; int r = ch >> 3, c = ch & 7;
      gload_lds16(Ag + (size_t)r * GK + ((c ^ (r & 7)) * 8), Al + ch * 8);
    }
    const unsigned short* Bg = Bw + (size_t)n0 * GK + kt * GBK;
    unsigned short* Bl = Bs + p * (GBN * GBK);
#pragma unroll
    for (int i = 0; i < 3; ++i) {
      int ch = i * 512 + t; int r = ch >> 3, c = ch & 7;
      gload_lds16(Bg + (size_t)r * GK + ((c ^ (r & 7)) * 8), Bl + ch * 8);
    }
  };

  STAGE(0, 0);
  STAGE(1, 1);

  for (int kt = 0; kt < GNT; ++kt) {
    const int cur = kt & 1;
    if (kt < GNT - 1) { asm volatile("s_waitcnt vmcnt(5)" ::: "memory"); }
    else              { asm volatile("s_waitcnt vmcnt(0)" ::: "memory"); }
    __builtin_amdgcn_sched_barrier(0);
    __builtin_amdgcn_s_barrier();
    __builtin_amdgcn_sched_barrier(0);
    asm volatile("" ::: "memory");

    const unsigned short* Al = As + cur * (GBM * GBK);
    const unsigned short* Bl = Bs + cur * (GBN * GBK);
#pragma unroll
    for (int kh = 0; kh < 2; ++kh) {
      bf16x8 af[4], bfn[3];
#pragma unroll
      for (int mf = 0; mf < 4; ++mf) {
        int r = wm * 64 + mf * 16 + li;
        af[mf] = *(const bf16x8*)(Al + r * 64 + (((kh * 4 + g) ^ (li & 7)) * 8));
      }
#pragma unroll
      for (int nf = 0; nf < 3; ++nf) {
        int r = wn * 48 + nf * 16 + li;
        bfn[nf] = *(const bf16x8*)(Bl + r * 64 + (((kh * 4 + g) ^ (li & 7)) * 8));
      }
      __builtin_amdgcn_s_setprio(1);
#pragma unroll
      for (int mf = 0; mf < 4; ++mf)
#pragma unroll
        for (int nf = 0; nf < 3; ++nf)
          acc[mf][nf] = __builtin_amdgcn_mfma_f32_16x16x32_bf16(
              af[mf], bfn[nf], acc[mf][nf], 0, 0, 0);
      __builtin_amdgcn_s_setprio(0);
    }
    asm volatile("" ::: "memory");
    __builtin_amdgcn_sched_barrier(0);
    __builtin_amdgcn_s_barrier();
    __builtin_amdgcn_sched_barrier(0);
    if (kt + 2 < GNT) STAGE(cur, kt + 2);
  }

  // ---- epilogue pass 1: Q/K scalar stores (coalesced cols) + V -> LT ----
  bool hasV = false;
  if (EPI == 0) {
    int matA = n0 >> 9, matB = (n0 + GBN - 1) >> 9;
    hasV = ((matA % 3) == 2) || ((matB % 3) == 2);
  }

#pragma unroll
  for (int mf = 0; mf < 4; ++mf)
#pragma unroll
    for (int nf = 0; nf < 3; ++nf) {
      int row0 = wm * 64 + mf * 16 + g * 4;   // tile row 0..127 (mult of 4)
      int colL = wn * 48 + nf * 16 + li;      // tile col 0..191
      int col  = n0 + colL;
      if (EPI == 0) {
        int mat = col >> 9, qkv = mat % 3;    // uniform within frag
        if (qkv == 2) {
          ushort4 o;
          o.x = f2bf(acc[mf][nf][0]); o.y = f2bf(acc[mf][nf][1]);
          o.z = f2bf(acc[mf][nf][2]); o.w = f2bf(acc[mf][nf][3]);
          *(ushort4*)(LT + colL * 132 + row0) = o;
        } else {
          int br = mat / 3;
          int within = col & 511;
          int h = within >> 7, d = within & 127;
          unsigned short* dst = (qkv == 0) ? Qs : Ksl;
#pragma unroll
          for (int rr = 0; rr < 4; ++rr) {
            int row = m0 + row0 + rr;
            int b = row >> 11, tt = row & 2047;
            dst[((size_t)((br * 2 + b) * 4 + h) * TSEQ + tt) * HDIM + d] =
                f2bf(acc[mf][nf][rr]);
          }
        }
      } else {
#pragma unroll
        for (int rr = 0; rr < 4; ++rr)
          Cout[(size_t)(m0 + row0 + rr) * DMODEL + col] = acc[mf][nf][rr];
      }
    }

  // ---- epilogue pass 2: LT -> coalesced V^T stores ----
  if (EPI == 0 && hasV) {
    __syncthreads();
    const int bx = m0 >> 11, tb0 = m0 & 2047;
#pragma unroll
    for (int j = 0; j < 6; ++j) {
      int ch = j * 512 + t;            // 0..3071 = 192 cols x 16 t-chunks
      int ci = ch >> 4;
      int col = n0 + ci;
      int mat = col >> 9;
      if (mat % 3 == 2) {
        int within = col & 511;
        int hh = within >> 7, dd = within & 127;
        int brx = mat / 3;
        int t0c = (ch & 15) * 8;
        ushort4 lo  = *(const ushort4*)(LT + ci * 132 + t0c);
        ushort4 hi4 = *(const ushort4*)(LT + ci * 132 + t0c + 4);
        union { ushort4 a[2]; bf16x8 v; } u;
        u.a[0] = lo; u.a[1] = hi4;
        *(bf16x8*)(Vs + (size_t)((brx * 2 + bx) * 4 + hh) * (TSEQ * HDIM)
                      + (size_t)dd * TSEQ + tb0 + t0c) = u.v;
      }
    }
  }
}

// ---------------------------------------------------------------------------
// RMSNorm + RoPE in place on Q,K slabs (bf16). One wave per row.
// ---------------------------------------------------------------------------
__global__ __launch_bounds__(256) void k_rope(
    unsigned short* __restrict__ Q, unsigned short* __restrict__ K,
    const float* __restrict__ qw, const float* __restrict__ kw)
{
  const int t = threadIdx.x, ln = t & 63, w = t >> 6;
  const int rid = blockIdx.x * 4 + w;          // 0..49151
  const int tt  = rid & (TSEQ - 1);
  const size_t base = (size_t)rid * HDIM;

  const float ang = (float)tt * exp2f(-0.31143075464f * (float)ln);
  float s, c;
  sincosf(ang, &s, &c);

#pragma unroll
  for (int which = 0; which < 2; ++which) {
    unsigned short* P = which ? K : Q;
    const float* Wn = which ? kw : qw;
    float x1 = bf2f(P[base + ln]);
    float x2 = bf2f(P[base + 64 + ln]);
    float ss = x1 * x1 + x2 * x2;
#pragma unroll
    for (int off = 1; off < 64; off <<= 1) ss += __shfl_xor(ss, off, 64);
    float rr = rsqrtf(ss * (1.0f / 128.0f) + 1.1920928955078125e-07f);
    float y1 = x1 * rr * Wn[ln];
    float y2 = x2 * rr * Wn[64 + ln];
    P[base + ln]      = f2bf(y1 * c - y2 * s);
    P[base + 64 + ln] = f2bf(y2 * c + y1 * s);
  }
}

// ---------------------------------------------------------------------------
// Flash attention (R13 structure + R15 defer-max). 32x32x16 MFMA, split-K,
// in-register P. R16: grid (8=bh, 16=qt, 2) so lid%8 == bh -> all qt blocks
// sharing a bh's Q/K/V slabs land on ONE XCD (L2-resident, T1).
// ---------------------------------------------------------------------------
#define ATT_SCALE 0.08838834764831845f

template<int MODE>
__device__ __forceinline__ void flash_phase(
    int qt, int bh,
    const unsigned short* __restrict__ Q, const unsigned short* __restrict__ K,
    const unsigned short* __restrict__ VT, unsigned short* __restrict__ AO,
    unsigned short* SH)
{
  const int b = bh >> 2, h = bh & 3;
  const int t = threadIdx.x, l = t & 63, w = t >> 6;
  const int hi = l >> 5, l31 = l & 31;
  const int wq = w & 3, gid = w >> 2;
  const size_t slab = (size_t)(MODE * 8 + bh) * (TSEQ * HDIM);
  const int q0 = qt * 128;

  unsigned short* KsG = SH + gid * 17920;        // [64][136] u16
  unsigned short* VtG = KsG + 8704;              // [128][72] u16

  bf16x8 qf[8];
  {
    const unsigned short* qp = Q + slab + (size_t)(q0 + wq*32 + l31) * HDIM + hi*8;
#pragma unroll
    for (int st = 0; st < 8; ++st) qf[st] = *(const bf16x8*)(qp + st*16);
  }

  f32x16 zero16;
#pragma unroll
  for (int e = 0; e < 16; ++e) zero16[e] = 0.f;
  f32x16 acc[4];
#pragma unroll
  for (int df = 0; df < 4; ++df) acc[df] = zero16;
  float m_run = -1e30f, l_run = 0.f;

  int n, ktbase, diagAt;
  if (MODE == 0)      { n = qt + 1;  ktbase = gid;          diagAt = n - 1; }
  else if (MODE == 1) { n = 16 - qt; ktbase = 2*qt + gid;   diagAt = 0; }
  else                { n = 16;      ktbase = gid;          diagAt = -1; }

  const int tl = t & 255;
  bf16x8 rk[4], rv[4];
  auto LOADT = [&](int kt) {
    const int k0 = kt * 64;
#pragma unroll
    for (int j = 0; j < 4; ++j) {
      int c = j * 256 + tl;
      rk[j] = *(const bf16x8*)(K  + slab + (size_t)(k0 + (c >> 4)) * HDIM + (c & 15) * 8);
      rv[j] = *(const bf16x8*)(VT + slab + (size_t)(c >> 3) * TSEQ + k0 + (c & 7) * 8);
    }
  };

  LOADT(ktbase);

  for (int i = 0; i < n; ++i) {
    const int kt = ktbase + 2 * i;
    const int k0 = kt * 64;
    __syncthreads();
#pragma unroll
    for (int j = 0; j < 4; ++j) {
      int c = j * 256 + tl;
      *(bf16x8*)(KsG + (c >> 4) * 136 + (c & 15) * 8) = rk[j];
      *(bf16x8*)(VtG + (c >> 3) * 72  + (c & 7) * 8)  = rv[j];
    }
    if (i + 1 < n) LOADT(kt + 2);
    __syncthreads();

    f32x16 sf0 = zero16, sf1 = zero16;
#pragma unroll
    for (int st = 0; st < 8; ++st) {
      bf16x8 kf0 = *(const bf16x8*)(KsG + l31 * 136 + st*16 + hi*8);
      bf16x8 kf1 = *(const bf16x8*)(KsG + (32 + l31) * 136 + st*16 + hi*8);
      __builtin_amdgcn_s_setprio(1);
      sf0 = __builtin_amdgcn_mfma_f32_32x32x16_bf16(kf0, qf[st], sf0, 0, 0, 0);
      sf1 = __builtin_amdgcn_mfma_f32_32x32x16_bf16(kf1, qf[st], sf1, 0, 0, 0);
      __builtin_amdgcn_s_setprio(0);
    }

    float pf[32];
#pragma unroll
    for (int r = 0; r < 16; ++r) { pf[r] = sf0[r] * ATT_SCALE; pf[16+r] = sf1[r] * ATT_SCALE; }

    if (MODE != 2 && i == diagAt) {
      const int qg = q0 + wq*32 + l31;
#pragma unroll
      for (int f = 0; f < 2; ++f)
#pragma unroll
        for (int r = 0; r < 16; ++r) {
          int kg = k0 + f*32 + 4*hi + (r & 3) + 8*(r >> 2);
          bool ok = (MODE == 0) ? (kg <= qg) : (kg >= qg);
          if (!ok) pf[f*16 + r] = -1e30f;
        }
    }

    float m = pf[0];
#pragma unroll
    for (int j = 1; j < 32; ++j) m = fmaxf(m, pf[j]);
    m = fmaxf(m, __shfl_xor(m, 32, 64));

    // T13 defer-max: rescale only when max grew by > 8 (P bounded by e^8)
    if (__any(m - m_run > 8.0f)) {
      float mn = fmaxf(m_run, m);
      float alpha = __expf(m_run - mn);
      m_run = mn;
      l_run *= alpha;
#pragma unroll
      for (int df = 0; df < 4; ++df) acc[df] *= alpha;
    }

    float rs0 = 0.f, rs1 = 0.f, rs2 = 0.f, rs3 = 0.f;
#pragma unroll
    for (int j = 0; j < 8; ++j) { pf[j]    = __expf(pf[j]    - m_run); rs0 += pf[j]; }
#pragma unroll
    for (int j = 8; j < 16; ++j){ pf[j]    = __expf(pf[j]    - m_run); rs1 += pf[j]; }
#pragma unroll
    for (int j = 0; j < 8; ++j) { pf[16+j] = __expf(pf[16+j] - m_run); rs2 += pf[16+j]; }
#pragma unroll
    for (int j = 8; j < 16; ++j){ pf[16+j] = __expf(pf[16+j] - m_run); rs3 += pf[16+j]; }
    float rs = (rs0 + rs1) + (rs2 + rs3);
    rs += __shfl_xor(rs, 32, 64);
    l_run += rs;

    unsigned int pb[2][8];
#pragma unroll
    for (int f = 0; f < 2; ++f) {
#pragma unroll
      for (int u = 0; u < 4; ++u) {
        pb[f][2*u]   = cvtpk(pf[f*16 + 4*u + 0], pf[f*16 + 4*u + 1]);
        pb[f][2*u+1] = cvtpk(pf[f*16 + 4*u + 2], pf[f*16 + 4*u + 3]);
      }
      plswap(pb[f][0], pb[f][2]);
      plswap(pb[f][1], pb[f][3]);
      plswap(pb[f][4], pb[f][6]);
      plswap(pb[f][5], pb[f][7]);
    }

#pragma unroll
    for (int s = 0; s < 4; ++s) {
      union { unsigned int u[4]; bf16x8 v; } pbv;
#pragma unroll
      for (int u = 0; u < 4; ++u) pbv.u[u] = pb[s >> 1][(s & 1) * 4 + u];
#pragma unroll
      for (int df = 0; df < 4; ++df) {
        bf16x8 vb = *(const bf16x8*)(VtG + (df*32 + l31) * 72 + s*16 + hi*8);
        __builtin_amdgcn_s_setprio(1);
        acc[df] = __builtin_amdgcn_mfma_f32_32x32x16_bf16(vb, pbv.v, acc[df], 0, 0, 0);
        __builtin_amdgcn_s_setprio(0);
      }
    }
  }

  // ---- split-K combine ----
  __syncthreads();
  float* EXf = (float*)SH;                       // [4][64][68] f32
  float* MLf = (float*)(SH + 35840);             // [4][64][2]  f32
  if (gid == 1) {
    MLf[(wq*64 + l)*2 + 0] = m_run;
    MLf[(wq*64 + l)*2 + 1] = l_run;
#pragma unroll
    for (int df = 0; df < 4; ++df)
#pragma unroll
      for (int u = 0; u < 4; ++u) {
        f32x4 ch = {acc[df][4*u], acc[df][4*u+1], acc[df][4*u+2], acc[df][4*u+3]};
        *(f32x4*)&EXf[(wq*64 + l)*68 + df*16 + u*4] = ch;
      }
  }
  __syncthreads();
  if (gid == 0) {
    float mB = MLf[(wq*64 + l)*2 + 0];
    float lB = MLf[(wq*64 + l)*2 + 1];
    float mF = fmaxf(m_run, mB);
    float a0 = __expf(m_run - mF), a1 = __expf(mB - mF);
    float inv = 1.0f / (l_run * a0 + lB * a1);
    a0 *= inv; a1 *= inv;
#pragma unroll
    for (int df = 0; df < 4; ++df)
#pragma unroll
      for (int u = 0; u < 4; ++u) {
        f32x4 cb = *(const f32x4*)&EXf[(wq*64 + l)*68 + df*16 + u*4];
#pragma unroll
        for (int e = 0; e < 4; ++e)
          acc[df][4*u+e] = acc[df][4*u+e] * a0 + cb[e] * a1;
      }
  }
  __syncthreads();

  // ---- transpose epilogue ----
  unsigned int* OT = (unsigned int*)SH;
  if (gid == 0) {
#pragma unroll
    for (int df = 0; df < 4; ++df)
#pragma unroll
      for (int u = 0; u < 4; ++u) {
        unsigned int d0 = cvtpk(acc[df][4*u+0], acc[df][4*u+1]);
        unsigned int d1 = cvtpk(acc[df][4*u+2], acc[df][4*u+3]);
        uint2 dd; dd.x = d0; dd.y = d1;
        *(uint2*)&OT[(wq*32 + l31)*68 + df*16 + 2*hi + 4*u] = dd;
      }
  }
  __syncthreads();
  {
    const int q = t >> 2, sg = t & 3;
    size_t rowbase = ((size_t)b * TSEQ + q0 + q) * DMODEL + MODE * 512 + h * HDIM;
#pragma unroll
    for (int u = 0; u < 4; ++u) {
      bf16x8 vv = *(const bf16x8*)&OT[q*68 + u*16 + sg*4];
      *(bf16x8*)(AO + rowbase + (u*16 + sg*4)*2) = vv;
    }
  }
}

// grid (8, 16, 2): x=bh (lid%8 -> XCD), y=qt, z: 0=causal+anti, 1=bidir.
__global__ __launch_bounds__(512, 2) void k_attn(
    const unsigned short* __restrict__ Q, const unsigned short* __restrict__ K,
    const unsigned short* __restrict__ VT, unsigned short* __restrict__ AO)
{
  __shared__ __align__(16) unsigned short SH[36864];   // 73,728 B

  const int bh = blockIdx.x;
  const int qt = blockIdx.y;
  if (blockIdx.z == 0) {
    flash_phase<0>(qt, bh, Q, K, VT, AO, SH);
    flash_phase<1>(qt, bh, Q, K, VT, AO, SH);
  } else {
    flash_phase<2>(qt, bh, Q, K, VT, AO, SH);
  }
}

// ---------------------------------------------------------------------------
extern "C" void kernel_launch(void* const* d_in, const int* in_sizes, int n_in,
                              void* d_out, int out_size, void* d_ws, size_t ws_size,
                              hipStream_t stream)
{
  (void)in_sizes; (void)n_in; (void)out_size; (void)ws_size;
  const float* qw  = (const float*)d_in[11];
  const float* kw  = (const float*)d_in[12];

  const size_t S = (size_t)NBR * 2 * NHB * TSEQ * HDIM;       // 6,291,456 elems
  unsigned short* Qs   = (unsigned short*)d_ws;                // S
  unsigned short* Ks   = Qs + S;                               // S
  unsigned short* Vs   = Ks + S;                               // S (holds V^T)
  unsigned short* AO   = Vs + S;                               // S
  unsigned short* Xbf  = AO + S;                               // S (= MROWS*DMODEL)
  unsigned short* Wbf  = Xbf + (size_t)MROWS * DMODEL;         // 9*512*1536
  unsigned short* WObf = Wbf + (size_t)9 * 512 * DMODEL;       // 1536*1536
  float* Cout = (float*)d_out;

  // fused conversion: X | 9 QKV weights | WO
  CVT cv;
  cv.s[0] = (const float*)d_in[0];
  for (int i = 0; i < 9; ++i) cv.s[1 + i] = (const float*)d_in[1 + i];
  cv.s[10] = (const float*)d_in[10];
  k_cvt_all<<<dim3(15360), dim3(256), 0, stream>>>(cv, Xbf, Wbf, WObf);

  // fused QKV projection: [4096, 4608] = X @ Wall^T (V written as V^T)
  k_gemm8<0><<<dim3(32, 24), dim3(512), 0, stream>>>(Xbf, Wbf, Qs, Ks, Vs, nullptr);
  k_rope<<<dim3(12288), dim3(256), 0, stream>>>(Qs, Ks, qw, kw);
  k_attn<<<dim3(8, 16, 2), dim3(512), 0, stream>>>(Qs, Ks, Vs, AO);
  // output projection: [4096, 1536] = AO @ wo^T
  k_gemm8<1><<<dim3(32, 8), dim3(512), 0, stream>>>(AO, WObf, nullptr, nullptr, nullptr, Cout);
}